// Round 6
// baseline (325.230 us; speedup 1.0000x reference)
//
#include <hip/hip_runtime.h>
#include <math.h>

// Problem constants: B=64, N=64, D=6, L=32, T=2048
#define TB 2048
#define LL 32
#define NP 64
#define DD 6
#define BB 64
#define NLANES 8        // lanes per DP problem
#define ROWS 4          // pattern rows per lane (L = 8*4 = 32)
#define CW 16           // columns per macro-step (tile width)
#define MSTEPS (TB/CW)  // 128
#define XSTRIDE 20      // floats per 16-float x block (80 B: bank-swizzled)
#define CSTRIDE 20      // floats per thread comm region (80 B: bank-swizzled)

// Recurrence:
//   D[0, j] = c[0, j]
//   D[i, j] = c[i, j] + w * min(D[i-1, j], D[i, j-1], D[i-1, j-1])
//   out[b,n,d,j] = sqrt(D[L-1, j])
//
// R3 lesson: 16 ds_bpermute gathers/mstep saturate the per-CU LDS pipe
// (~26 bank-cyc each x 12 waves/CU ~= measured 6300 cyc/mstep); latency fixes
// were no-ops. R4/R5: pass the boundary row via LDS tiles instead —
// 4 ds_write_b128 (producer) + 4 ds_read_b128 (consumer) + 4 ds_read_b128 (x)
// per mstep, all conflict-optimal at an 80-B stride (start bank 20*tid mod 32
// covers all 32 banks; 8 lanes/bank is the b128 hardware floor; x reads are
// 8-way same-address broadcast). Producer lane k-1 and consumer lane k are in
// the SAME wave: hardware keeps per-wave DS ops in order, so write(m) ->
// read(m+1) needs no barrier. The empty asm "memory" fence at the end of the
// body stops the compiler/scheduler from hoisting next-iteration reads above
// this iteration's writes (it could otherwise prove the per-thread regions
// disjoint). INF-initialized comm + fma(w,INF,c)=INF keeps ramp-in exact;
// ramp-out garbage is finite and only ever read by invalid lanes.

__global__ __launch_bounds__(256) void dtw_kernel(
    const float* __restrict__ x,      // (B, D, T)
    const float* __restrict__ patts,  // (N, L)
    const float* __restrict__ wptr,   // scalar
    float* __restrict__ out)          // (B, N, D, T)
{
    __shared__ float xs[MSTEPS * XSTRIDE];    // 10240 B
    __shared__ float comm[256 * CSTRIDE];     // 20480 B

    const int bid  = blockIdx.x;      // B*D*2 blocks
    const int half = bid & 1;         // which 32 of the 64 patterns
    const int bd   = bid >> 1;        // b*D + d
    const int tid  = threadIdx.x;

    const float INF = __builtin_inff();

    // INF-init own comm region (neighbor reads it during ramp-in; INF
    // self-propagates through fma(w,INF,c)).
    float* my = comm + tid * CSTRIDE;
    const float4 inf4 = make_float4(INF, INF, INF, INF);
    *(float4*)(my + 0)  = inf4;
    *(float4*)(my + 4)  = inf4;
    *(float4*)(my + 8)  = inf4;
    *(float4*)(my + 12) = inf4;

    // Stage x[b,d,:] into xs, 16 floats per block at 20-float stride.
    const float4* xrow = (const float4*)(x + (size_t)bd * TB);
    #pragma unroll
    for (int i = 0; i < 2; ++i) {
        const int idx = tid + i * 256;          // float4 index 0..511
        const int qb = idx >> 2, sub = idx & 3;
        *(float4*)(xs + qb * XSTRIDE + sub * 4) = xrow[idx];
    }
    __syncthreads();

    const int g = tid >> 3;           // group 0..31 (one pattern each)
    const int k = tid & 7;            // lane within group
    const int n = half * 32 + g;

    const float w = wptr[0];
    const float4 pv = *(const float4*)(patts + n * LL + k * ROWS);
    const float p0 = pv.x, p1 = pv.y, p2 = pv.z, p3 = pv.w;

    const int b = bd / DD, d = bd - (bd / DD) * DD;
    float* __restrict__ orow = out + (((size_t)b * NP + n) * DD + d) * TB;

    const bool k0 = (k == 0), k7 = (k == NLANES - 1);

    // Neighbor region: lane k reads lane k-1's tile (k0 lanes read data that
    // only feeds the m0 path, discarded by the k0 select).
    const float* nb = comm + (tid == 0 ? 0 : tid - 1) * CSTRIDE;

    float a0 = INF, a1 = INF, a2 = INF, a3 = INF;   // left-column carries
    float diagC = INF;                              // diag for tile col 0

    for (int m = 0; m < MSTEPS + NLANES - 1; ++m) {
        const int q = m - k;
        const bool valid = ((unsigned)q < (unsigned)MSTEPS);
        const int qq = valid ? q : 0;
        const float* xb = xs + qq * XSTRIDE;

        // ---- LDS read phase: neighbor boundary row + x tile (8 b128) ----
        const float4 rA = *(const float4*)(nb + 0);
        const float4 rB = *(const float4*)(nb + 4);
        const float4 rC = *(const float4*)(nb + 8);
        const float4 rD = *(const float4*)(nb + 12);
        const float4 xA = *(const float4*)(xb + 0);
        const float4 xB = *(const float4*)(xb + 4);
        const float4 xC = *(const float4*)(xb + 8);
        const float4 xD = *(const float4*)(xb + 12);

        const float recv[CW] = {rA.x, rA.y, rA.z, rA.w,  rB.x, rB.y, rB.z, rB.w,
                                rC.x, rC.y, rC.z, rC.w,  rD.x, rD.y, rD.z, rD.w};
        const float xv[CW]   = {xA.x, xA.y, xA.z, xA.w,  xB.x, xB.y, xB.z, xB.w,
                                xC.x, xC.y, xC.z, xC.w,  xD.x, xD.y, xD.z, xD.w};

        // ---- compute phase: 64 cells, pure VALU ----
        float r3[CW];
        float diag = diagC;
        #pragma unroll
        for (int c = 0; c < CW; ++c) {
            const float xvc = xv[c];
            float t0 = p0 - xvc, t1 = p1 - xvc, t2 = p2 - xvc, t3 = p3 - xvc;
            const float c0 = t0 * t0, c1 = t1 * t1, c2 = t2 * t2, c3 = t3 * t3;
            const float up = recv[c];
            const float l0 = a0, l1 = a1, l2 = a2, l3 = a3;

            const float m0 = fminf(fminf(l0, up), diag);   // v_min3
            const float v0 = k0 ? c0 : fmaf(w, m0, c0);    // row 0: free start
            const float m1 = fminf(fminf(l1, v0), l0);
            const float v1 = fmaf(w, m1, c1);
            const float m2 = fminf(fminf(l2, v1), l1);
            const float v2 = fmaf(w, m2, c2);
            const float m3 = fminf(fminf(l3, v2), l2);
            const float v3 = fmaf(w, m3, c3);

            a0 = v0; a1 = v1; a2 = v2; a3 = v3;
            diag = up;
            r3[c] = v3;
        }
        diagC = rD.w;   // recv[15]: diag seed for next block's col 0

        // ---- publish boundary row: 4x ds_write_b128 (plain stores) ----
        *(float4*)(my + 0)  = make_float4(r3[0],  r3[1],  r3[2],  r3[3]);
        *(float4*)(my + 4)  = make_float4(r3[4],  r3[5],  r3[6],  r3[7]);
        *(float4*)(my + 8)  = make_float4(r3[8],  r3[9],  r3[10], r3[11]);
        *(float4*)(my + 12) = make_float4(r3[12], r3[13], r3[14], r3[15]);

        // Row L-1 output: 64 B contiguous per macro-step.
        if (k7 && valid) {
            float4* op = (float4*)(orow + q * CW);
            op[0] = make_float4(sqrtf(r3[0]),  sqrtf(r3[1]),  sqrtf(r3[2]),  sqrtf(r3[3]));
            op[1] = make_float4(sqrtf(r3[4]),  sqrtf(r3[5]),  sqrtf(r3[6]),  sqrtf(r3[7]));
            op[2] = make_float4(sqrtf(r3[8]),  sqrtf(r3[9]),  sqrtf(r3[10]), sqrtf(r3[11]));
            op[3] = make_float4(sqrtf(r3[12]), sqrtf(r3[13]), sqrtf(r3[14]), sqrtf(r3[15]));
        }

        // Compiler-level memory fence: next iteration's nb/xs reads must not
        // hoist above this iteration's comm writes (hardware keeps per-wave
        // DS ops in order; this pins the compiler to the same order).
        asm volatile("" ::: "memory");
    }
}

extern "C" void kernel_launch(void* const* d_in, const int* in_sizes, int n_in,
                              void* d_out, int out_size, void* d_ws, size_t ws_size,
                              hipStream_t stream) {
    const float* x     = (const float*)d_in[0];
    const float* patts = (const float*)d_in[1];
    const float* wptr  = (const float*)d_in[2];
    float* out = (float*)d_out;

    dim3 grid(BB * DD * 2);   // 768 blocks: one (b,d) per pair of blocks
    dim3 block(256);          // 32 pattern-groups of 8 lanes
    dtw_kernel<<<grid, block, 0, stream>>>(x, patts, wptr, out);
}